// Round 1
// baseline (107.949 us; speedup 1.0000x reference)
//
#include <hip/hip_runtime.h>
#include <math.h>

#define NQ 4
#define DIM 16
#define BB 4
#define SS 512
#define EE 512
#define ROWS (BB * SS)   // 2048

// ---------------------------------------------------------------------------
// Kernel 1: build the fixed circuit unitary U (16x16 complex) from the
// quantum weights, then Mr[k][l] = Re( sum_idx z[idx] * conj(U[idx,k]) * U[idx,l] ).
// score(amp) = amp^T Mr amp for the REAL encoded amplitude vector amp.
// One block of 256 threads: threads 0..15 each simulate one basis column.
// ---------------------------------------------------------------------------
__global__ void k_circuit(const float* __restrict__ qw, float* __restrict__ Mr_out) {
    __shared__ float Ur[DIM][DIM];  // [idx][col]
    __shared__ float Ui[DIM][DIM];
    int t = threadIdx.x;
    if (t < DIM) {
        float vr[DIM], vi[DIM];
#pragma unroll
        for (int i = 0; i < DIM; ++i) { vr[i] = (i == t) ? 1.f : 0.f; vi[i] = 0.f; }
#pragma unroll
        for (int layer = 0; layer < 2; ++layer) {
#pragma unroll
            for (int w = 0; w < NQ; ++w) {
                float a = qw[(layer * NQ + w) * 3 + 0] * 0.5f;
                float b = qw[(layer * NQ + w) * 3 + 1] * 0.5f;
                float c = qw[(layer * NQ + w) * 3 + 2] * 0.5f;
                float sa, ca, sb, cb, sc, cc;
                sincosf(a, &sa, &ca);
                sincosf(b, &sb, &cb);
                sincosf(c, &sc, &cc);
                // M = RY(b) @ RX(a)
                float m00r = cb * ca, m00i = sb * sa;
                float m01r = -sb * ca, m01i = -cb * sa;
                float m10r = sb * ca, m10i = -cb * sa;
                float m11r = cb * ca, m11i = -sb * sa;
                // G = RZ(c) @ M : row0 *= e^{-ic}, row1 *= e^{+ic}
                float g00r = cc * m00r + sc * m00i, g00i = cc * m00i - sc * m00r;
                float g01r = cc * m01r + sc * m01i, g01i = cc * m01i - sc * m01r;
                float g10r = cc * m10r - sc * m10i, g10i = cc * m10i + sc * m10r;
                float g11r = cc * m11r - sc * m11i, g11i = cc * m11i + sc * m11r;
                int mask = 1 << (3 - w);  // wire w <-> bit (3-w) of flat idx
#pragma unroll
                for (int idx = 0; idx < DIM; ++idx) {
                    if (idx & mask) continue;
                    int i1 = idx | mask;
                    float r0 = vr[idx], i0 = vi[idx], r1 = vr[i1], i1v = vi[i1];
                    vr[idx] = g00r * r0 - g00i * i0 + g01r * r1 - g01i * i1v;
                    vi[idx] = g00r * i0 + g00i * r0 + g01r * i1v + g01i * r1;
                    vr[i1]  = g10r * r0 - g10i * i0 + g11r * r1 - g11i * i1v;
                    vi[i1]  = g10r * i0 + g10i * r0 + g11r * i1v + g11i * r1;
                }
            }
            // CNOT chain: (ctrl,tgt) wires (0,1),(1,2),(2,3),(3,0)
            const int cwire[4] = {0, 1, 2, 3};
            const int twire[4] = {1, 2, 3, 0};
#pragma unroll
            for (int e = 0; e < 4; ++e) {
                int cmask = 1 << (3 - cwire[e]);
                int tmask = 1 << (3 - twire[e]);
                float nr[DIM], ni[DIM];
#pragma unroll
                for (int idx = 0; idx < DIM; ++idx) {
                    int src = (idx & cmask) ? (idx ^ tmask) : idx;
                    nr[idx] = vr[src]; ni[idx] = vi[src];
                }
#pragma unroll
                for (int idx = 0; idx < DIM; ++idx) { vr[idx] = nr[idx]; vi[idx] = ni[idx]; }
            }
        }
#pragma unroll
        for (int i = 0; i < DIM; ++i) { Ur[i][t] = vr[i]; Ui[i][t] = vi[i]; }
    }
    __syncthreads();
    // each of 256 threads computes one Mr entry
    {
        int k = t >> 4, l = t & 15;
        float acc = 0.f;
#pragma unroll
        for (int idx = 0; idx < DIM; ++idx) {
            float z = 4.f - 2.f * (float)__popc(idx);
            acc += z * (Ur[idx][k] * Ur[idx][l] + Ui[idx][k] * Ui[idx][l]);
        }
        Mr_out[t] = acc;
    }
}

// ---------------------------------------------------------------------------
// Kernel 2: q = tanh(x@Wq+bq), k = tanh(x@Wk+bk), v = x@Wv+bv.  One wave per
// row of x; block 256 = 4 waves; grid 512.
// ---------------------------------------------------------------------------
__global__ __launch_bounds__(256) void k_qkv(
    const float* __restrict__ x,
    const float* __restrict__ Wq, const float* __restrict__ bq,
    const float* __restrict__ Wk, const float* __restrict__ bk,
    const float* __restrict__ Wv, const float* __restrict__ bv,
    float* __restrict__ q, float* __restrict__ k, float* __restrict__ v) {
    int row = blockIdx.x * 4 + (threadIdx.x >> 6);
    int lane = threadIdx.x & 63;
    const float* xr = x + (size_t)row * EE;
    float aq[4] = {0, 0, 0, 0}, ak[4] = {0, 0, 0, 0}, av[4] = {0, 0, 0, 0};
    for (int e = lane; e < EE; e += 64) {
        float xv = xr[e];
#pragma unroll
        for (int c = 0; c < 4; ++c) {
            aq[c] += xv * Wq[e * 4 + c];
            ak[c] += xv * Wk[e * 4 + c];
            av[c] += xv * Wv[e * 4 + c];
        }
    }
#pragma unroll
    for (int off = 32; off > 0; off >>= 1) {
#pragma unroll
        for (int c = 0; c < 4; ++c) {
            aq[c] += __shfl_down(aq[c], off, 64);
            ak[c] += __shfl_down(ak[c], off, 64);
            av[c] += __shfl_down(av[c], off, 64);
        }
    }
    if (lane == 0) {
#pragma unroll
        for (int c = 0; c < 4; ++c) {
            q[row * 4 + c] = tanhf(aq[c] + bq[c]);
            k[row * 4 + c] = tanhf(ak[c] + bk[c]);
            v[row * 4 + c] = av[c] + bv[c];
        }
    }
}

// ---------------------------------------------------------------------------
// Kernel 3: per (b,i): scores over j via quadratic form, softmax, write attn
// row, reduce attended = sum_j attn*v[j].  Block 512 threads = 8 waves,
// grid 2048 (one block per query row).
// ---------------------------------------------------------------------------
__global__ __launch_bounds__(512) void k_attn(
    const float* __restrict__ q, const float* __restrict__ kk,
    const float* __restrict__ v, const float* __restrict__ Mr,
    float* __restrict__ attn_out, float* __restrict__ attended) {
    int row = blockIdx.x;        // b*S + i
    int b = row >> 9;            // / 512
    int j = threadIdx.x;
    int wid = threadIdx.x >> 6, lane = threadIdx.x & 63;

    __shared__ float sM[256];
    __shared__ float sq[4];
    __shared__ float rmax[8], rsum[8], rv[8][4];

    if (threadIdx.x < 256) sM[threadIdx.x] = Mr[threadIdx.x];
    if (threadIdx.x < 4) sq[threadIdx.x] = q[row * 4 + threadIdx.x];
    __syncthreads();

    const float* kr = kk + (size_t)(b * SS + j) * 4;
    float h0 = 0.5f * tanhf(sq[0] + kr[0]);
    float h1 = 0.5f * tanhf(sq[1] + kr[1]);
    float h2 = 0.5f * tanhf(sq[2] + kr[2]);
    float h3 = 0.5f * tanhf(sq[3] + kr[3]);
    float s0, c0, s1, c1, s2, c2, s3, c3;
    sincosf(h0, &s0, &c0);
    sincosf(h1, &s1, &c1);
    sincosf(h2, &s2, &c2);
    sincosf(h3, &s3, &c3);
    // amp[idx], idx = b0*8+b1*4+b2*2+b3 (wire0 = MSB)
    float ab[4] = {c0 * c1, c0 * s1, s0 * c1, s0 * s1};
    float cd[4] = {c2 * c3, c2 * s3, s2 * c3, s2 * s3};
    float A[16];
#pragma unroll
    for (int i2 = 0; i2 < 4; ++i2)
#pragma unroll
        for (int j2 = 0; j2 < 4; ++j2) A[i2 * 4 + j2] = ab[i2] * cd[j2];

    float score = 0.f;
#pragma unroll
    for (int k2 = 0; k2 < 16; ++k2) {
        float y = 0.f;
#pragma unroll
        for (int l2 = 0; l2 < 16; ++l2) y += sM[k2 * 16 + l2] * A[l2];
        score += A[k2] * y;
    }
    float sc = score * 0.5f;     // / sqrt(N_QUBITS)

    // block softmax over 512 threads
    float m = sc;
#pragma unroll
    for (int off = 32; off > 0; off >>= 1) m = fmaxf(m, __shfl_xor(m, off, 64));
    if (lane == 0) rmax[wid] = m;
    __syncthreads();
    float bm = rmax[0];
#pragma unroll
    for (int i = 1; i < 8; ++i) bm = fmaxf(bm, rmax[i]);

    float ex = expf(sc - bm);
    float sum = ex;
#pragma unroll
    for (int off = 32; off > 0; off >>= 1) sum += __shfl_xor(sum, off, 64);
    if (lane == 0) rsum[wid] = sum;
    __syncthreads();
    float bs = 0.f;
#pragma unroll
    for (int i = 0; i < 8; ++i) bs += rsum[i];

    float aj = ex / bs;
    attn_out[(size_t)row * SS + j] = aj;

    // attended[row, w] = sum_j aj * v[b,j,w]
    const float* vr = v + (size_t)(b * SS + j) * 4;
#pragma unroll
    for (int w = 0; w < 4; ++w) {
        float p = aj * vr[w];
#pragma unroll
        for (int off = 32; off > 0; off >>= 1) p += __shfl_xor(p, off, 64);
        if (lane == 0) rv[wid][w] = p;
    }
    __syncthreads();
    if (threadIdx.x < 4) {
        float s = 0.f;
#pragma unroll
        for (int i = 0; i < 8; ++i) s += rv[i][threadIdx.x];
        attended[row * 4 + threadIdx.x] = s;
    }
}

// ---------------------------------------------------------------------------
// Kernel 4: out[row, e] = sum_w attended[row,w] * Wout[w,e] + bout[e]
// float4 per thread; 128 threads per row.
// ---------------------------------------------------------------------------
__global__ __launch_bounds__(256) void k_out(
    const float* __restrict__ attended, const float* __restrict__ Wout,
    const float* __restrict__ bout, float* __restrict__ out) {
    int tid = blockIdx.x * blockDim.x + threadIdx.x;  // 0 .. 2048*128
    int row = tid >> 7;
    int e4 = (tid & 127) * 4;
    float a0 = attended[row * 4 + 0];
    float a1 = attended[row * 4 + 1];
    float a2 = attended[row * 4 + 2];
    float a3 = attended[row * 4 + 3];
    float4 w0 = *(const float4*)(Wout + 0 * EE + e4);
    float4 w1 = *(const float4*)(Wout + 1 * EE + e4);
    float4 w2 = *(const float4*)(Wout + 2 * EE + e4);
    float4 w3 = *(const float4*)(Wout + 3 * EE + e4);
    float4 bb = *(const float4*)(bout + e4);
    float4 o;
    o.x = a0 * w0.x + a1 * w1.x + a2 * w2.x + a3 * w3.x + bb.x;
    o.y = a0 * w0.y + a1 * w1.y + a2 * w2.y + a3 * w3.y + bb.y;
    o.z = a0 * w0.z + a1 * w1.z + a2 * w2.z + a3 * w3.z + bb.z;
    o.w = a0 * w0.w + a1 * w1.w + a2 * w2.w + a3 * w3.w + bb.w;
    *(float4*)(out + (size_t)row * EE + e4) = o;
}

extern "C" void kernel_launch(void* const* d_in, const int* in_sizes, int n_in,
                              void* d_out, int out_size, void* d_ws, size_t ws_size,
                              hipStream_t stream) {
    const float* x    = (const float*)d_in[0];
    const float* Wq   = (const float*)d_in[1];
    const float* bq   = (const float*)d_in[2];
    const float* Wk   = (const float*)d_in[3];
    const float* bk   = (const float*)d_in[4];
    const float* Wv   = (const float*)d_in[5];
    const float* bv   = (const float*)d_in[6];
    const float* qw   = (const float*)d_in[7];
    const float* Wout = (const float*)d_in[8];
    const float* bout = (const float*)d_in[9];

    float* out  = (float*)d_out;                 // [B,S,E] = 1048576 floats
    float* attn = out + (size_t)ROWS * EE;       // [B,S,S] = 1048576 floats

    float* ws  = (float*)d_ws;
    float* Mr  = ws;                  // 256
    float* q   = ws + 256;            // 8192
    float* k   = q + ROWS * 4;        // 8192
    float* v   = k + ROWS * 4;        // 8192
    float* att = v + ROWS * 4;        // 8192

    k_circuit<<<1, 256, 0, stream>>>(qw, Mr);
    k_qkv<<<ROWS / 4, 256, 0, stream>>>(x, Wq, bq, Wk, bk, Wv, bv, q, k, v);
    k_attn<<<ROWS, 512, 0, stream>>>(q, k, v, Mr, attn, att);
    k_out<<<(ROWS * 128) / 256, 256, 0, stream>>>(att, Wout, bout, out);
}